// Round 1
// baseline (255.898 us; speedup 1.0000x reference)
//
#include <hip/hip_runtime.h>
#include <hip/hip_fp16.h>
#include <math.h>

#define EMB_DIM 128
#define FINE_BITS 9
#define FINE_W 512
#define MAXB 256            // max coarse buckets (N <= 131072)
#define CHUNK 4096          // edges per scatter block

// ---------------------------------------------------------------------------
// K1 (fused): blocks [0,nchunks): col-side coarse scatter + row-side degree
// via direct global atomicAdd (row bucket machinery deleted — it only ever
// produced a histogram). Blocks [nchunks,...): f32->fp16 embedding convert.
// Cursors/deg are RELATIVE (zeroed by one memset); abs base = bucket*slack.
__global__ __launch_bounds__(256) void scatter_cvt_kernel(
    const int* __restrict__ row, const int* __restrict__ col,
    int* __restrict__ colCur, int* __restrict__ deg,
    unsigned int* __restrict__ colBucket,
    const float* __restrict__ emb, __half* __restrict__ emb16, long long n8,
    int slack, int nchunks, int e) {
    int bid = blockIdx.x;
    if (bid >= nchunks) {
        // ---- cvt tail: 8 floats -> 8 halves per thread ----
        long long t = (long long)(bid - nchunks) * 256 + threadIdx.x;
        if (t < n8) {
            const float4* src = (const float4*)(emb) + t * 2;
            float4 a = src[0];
            float4 b = src[1];
            __half h[8];
            h[0] = __float2half(a.x); h[1] = __float2half(a.y);
            h[2] = __float2half(a.z); h[3] = __float2half(a.w);
            h[4] = __float2half(b.x); h[5] = __float2half(b.y);
            h[6] = __float2half(b.z); h[7] = __float2half(b.w);
            ((uint4*)emb16)[t] = *(const uint4*)h;
        }
        return;
    }
    __shared__ int lh[MAXB], lb[MAXB];
    int base = bid * CHUNK;
    int lim = min(base + CHUNK, e);

    for (int t = threadIdx.x; t < MAXB; t += 256) lh[t] = 0;
    __syncthreads();
    for (int i = base + threadIdx.x; i < lim; i += 256)
        atomicAdd(&lh[col[i] >> FINE_BITS], 1);
    __syncthreads();
    for (int t = threadIdx.x; t < MAXB; t += 256)
        lb[t] = lh[t] ? (t * slack + atomicAdd(&colCur[t], lh[t])) : 0;
    __syncthreads();
    for (int t = threadIdx.x; t < MAXB; t += 256) lh[t] = 0;
    __syncthreads();
    for (int i = base + threadIdx.x; i < lim; i += 256) {
        int c = col[i], r = row[i];
        atomicAdd(&deg[r], 1);          // avg 16 hits/counter -> low contention
        int cb = c >> FINE_BITS;
        int p = lb[cb] + atomicAdd(&lh[cb], 1);
        if (p < (cb + 1) * slack)
            colBucket[p] = ((unsigned)r << FINE_BITS) | (unsigned)(c & (FINE_W - 1));
    }
}

// ---------------------------------------------------------------------------
// K2: 1024-thread blocks, one per coarse col bucket. Fine counting-sort
// (LDS hist + inclusive scan, absolute placement, zero global atomics).
// Also emits dis[node] = rsqrt(1+deg) (deg complete after K1).
__global__ __launch_bounds__(1024) void fine_kernel(
    const unsigned int* __restrict__ colBucket, const int* __restrict__ colCurF,
    const int* __restrict__ deg,
    int* __restrict__ offsets, int* __restrict__ ends, int* __restrict__ srcs,
    float* __restrict__ dis, int slack, int n) {
    __shared__ int fh[FINE_W];
    __shared__ int sc[FINE_W];
    __shared__ int fb[FINE_W];
    int b = blockIdx.x;
    unsigned t = threadIdx.x;
    int start = b * slack;
    int end = start + min(colCurF[b], slack);
    if (t < FINE_W) fh[t] = 0;
    __syncthreads();
    for (int i = start + (int)t; i < end; i += 1024)
        atomicAdd(&fh[colBucket[i] & (FINE_W - 1)], 1);
    __syncthreads();
    if (t < FINE_W) sc[t] = fh[t];
    __syncthreads();
    // inclusive Hillis-Steele scan over 512 bins
    for (int d = 1; d < FINE_W; d <<= 1) {
        int v = (t < FINE_W && t >= (unsigned)d) ? sc[t - d] : 0;
        __syncthreads();
        if (t < FINE_W) sc[t] += v;
        __syncthreads();
    }
    int nodeBase = b << FINE_BITS;
    if (t < FINE_W) {
        int st = start + sc[t] - fh[t];   // exclusive prefix
        fb[t] = st;
        int node = nodeBase + (int)t;
        if (node < n) {
            offsets[node] = st;
            ends[node] = st + fh[t];
            dis[node] = rsqrtf(1.0f + (float)deg[node]);  // +1 = self loop
        }
    }
    __syncthreads();
    for (int i = start + (int)t; i < end; i += 1024) {
        unsigned v = colBucket[i];
        int p = atomicAdd(&fb[v & (FINE_W - 1)], 1);
        srcs[p] = (int)(v >> FINE_BITS);
    }
}

// ---------------------------------------------------------------------------
// K3: gather. 16 lanes/node, 8 floats acc/lane, one uint4 fp16 load per
// edge per lane, unroll-4 (4 independent srcs->dis->row chains in flight,
// ~45 VGPR -> stays under the 64-VGPR occupancy step). Self-loop folded as
// an edge with norm=dc^2.
template <bool FP16>
__global__ __launch_bounds__(256) void gather_kernel(
    const __half* __restrict__ emb16, const float* __restrict__ emb,
    const float* __restrict__ dis, const int* __restrict__ offsets,
    const int* __restrict__ ends, const int* __restrict__ srcs,
    float* __restrict__ out, int n) {
    long long t = (long long)blockIdx.x * blockDim.x + threadIdx.x;
    int node = (int)(t >> 4);
    int lane = (int)(t & 15);
    if (node >= n) return;

    float dc = dis[node];
    float s = dc * dc;
    float4 acc0 = {0, 0, 0, 0}, acc1 = {0, 0, 0, 0};

#define LD16(SRC, HA) \
    uint4 HA = ((const uint4*)(emb16 + (long long)(SRC) * EMB_DIM))[lane];

#define FMA16(HA, NRM)                                                          \
    {                                                                           \
        const __half2* pa = (const __half2*)&HA;                                \
        float2 f0 = __half22float2(pa[0]), f1 = __half22float2(pa[1]);          \
        float2 f2 = __half22float2(pa[2]), f3 = __half22float2(pa[3]);          \
        acc0.x += (NRM) * f0.x; acc0.y += (NRM) * f0.y;                         \
        acc0.z += (NRM) * f1.x; acc0.w += (NRM) * f1.y;                         \
        acc1.x += (NRM) * f2.x; acc1.y += (NRM) * f2.y;                         \
        acc1.z += (NRM) * f3.x; acc1.w += (NRM) * f3.y;                         \
    }

#define LD32(SRC, VA, VB)                                                       \
    float4 VA, VB;                                                              \
    {                                                                           \
        const float4* fr = (const float4*)(emb + (long long)(SRC) * EMB_DIM);   \
        VA = fr[2 * lane]; VB = fr[2 * lane + 1];                               \
    }

#define FMA32(VA, VB, NRM)                                                      \
    {                                                                           \
        acc0.x += (NRM) * VA.x; acc0.y += (NRM) * VA.y;                         \
        acc0.z += (NRM) * VA.z; acc0.w += (NRM) * VA.w;                         \
        acc1.x += (NRM) * VB.x; acc1.y += (NRM) * VB.y;                         \
        acc1.z += (NRM) * VB.z; acc1.w += (NRM) * VB.w;                         \
    }

    int i = offsets[node];
    int end = ends[node];

    if (FP16) {
        { LD16(node, hs) FMA16(hs, s) }
        for (; i + 4 <= end; i += 4) {
            int s0 = srcs[i], s1 = srcs[i + 1], s2 = srcs[i + 2], s3 = srcs[i + 3];
            float n0 = dc * dis[s0], n1 = dc * dis[s1];
            float n2 = dc * dis[s2], n3 = dc * dis[s3];
            LD16(s0, h0) LD16(s1, h1) LD16(s2, h2) LD16(s3, h3)
            FMA16(h0, n0) FMA16(h1, n1) FMA16(h2, n2) FMA16(h3, n3)
        }
        for (; i < end; ++i) {
            int s0 = srcs[i];
            float n0 = dc * dis[s0];
            LD16(s0, h0) FMA16(h0, n0)
        }
    } else {
        { LD32(node, va, vb) FMA32(va, vb, s) }
        for (; i + 2 <= end; i += 2) {
            int s0 = srcs[i], s1 = srcs[i + 1];
            float n0 = dc * dis[s0], n1 = dc * dis[s1];
            LD32(s0, a0, b0) LD32(s1, a1, b1)
            FMA32(a0, b0, n0) FMA32(a1, b1, n1)
        }
        if (i < end) {
            int s0 = srcs[i];
            float n0 = dc * dis[s0];
            LD32(s0, a0, b0) FMA32(a0, b0, n0)
        }
    }
#undef LD16
#undef FMA16
#undef LD32
#undef FMA32

    float4* orow = (float4*)(out + (long long)node * EMB_DIM);
    orow[2 * lane] = acc0;
    orow[2 * lane + 1] = acc1;
}

extern "C" void kernel_launch(void* const* d_in, const int* in_sizes, int n_in,
                              void* d_out, int out_size, void* d_ws, size_t ws_size,
                              hipStream_t stream) {
    const int E = in_sizes[0] / 2;            // edge_index is (2, E) int32
    const int N = in_sizes[1] / EMB_DIM;      // embedding is (N, 128) f32
    const int nbuck = (N + FINE_W - 1) >> FINE_BITS;   // 196 for N=100000

    const int* edge_index = (const int*)d_in[0];
    const int* row = edge_index;              // sources
    const int* col = edge_index + E;          // destinations
    const float* emb = (const float*)d_in[1];
    float* out = (float*)d_out;

    // slack per bucket: mean + 25% + 1024 (>>10 sigma for random edges)
    const int expected = (int)(((long long)E * FINE_W + N - 1) / N);
    const int slack = expected + (expected >> 2) + 1024;
    const size_t bucketEntries = (size_t)nbuck * slack;

    char* ws = (char*)d_ws;
    size_t off = 0;
    auto alloc = [&](size_t bytes) -> void* {
        off = (off + 255) & ~(size_t)255;
        void* p = ws + off;
        off += bytes;
        return p;
    };

    size_t szEmb16 = (size_t)N * EMB_DIM * 2;
    size_t needCommon = (size_t)MAXB * 4 + (size_t)N * 16 +
                        bucketEntries * 8 + 16 * 256;
    bool useFp16 = (needCommon + szEmb16) <= ws_size;

    int*            colCur    = (int*)alloc((size_t)MAXB * 4);  // adjacent to deg
    int*            deg       = (int*)alloc((size_t)N * 4);
    int*            offsets   = (int*)alloc((size_t)N * 4);
    int*            ends      = (int*)alloc((size_t)N * 4);
    float*          dis       = (float*)alloc((size_t)N * 4);
    unsigned int*   colBucket = (unsigned int*)alloc(bucketEntries * 4);
    int*            srcs      = (int*)alloc(bucketEntries * 4);
    __half*         emb16     = useFp16 ? (__half*)alloc(szEmb16) : (__half*)nullptr;

    const int B = 256;
    const int nchunks = (E + CHUNK - 1) / CHUNK;
    long long n8 = useFp16 ? (long long)N * EMB_DIM / 8 : 0;
    int cvtBlocks = useFp16 ? (int)((n8 + B - 1) / B) : 0;

    // zero relative cursors + degree histogram (adjacent, one memset)
    hipMemsetAsync(colCur, 0, (size_t)MAXB * 4 + (size_t)N * 4, stream);

    scatter_cvt_kernel<<<nchunks + cvtBlocks, B, 0, stream>>>(
        row, col, colCur, deg, colBucket, emb, emb16, n8, slack, nchunks, E);

    fine_kernel<<<nbuck, 1024, 0, stream>>>(
        colBucket, colCur, deg, offsets, ends, srcs, dis, slack, N);

    long long gather_threads = (long long)N * 16;
    int gblocks = (int)((gather_threads + B - 1) / B);
    if (useFp16) {
        gather_kernel<true><<<gblocks, B, 0, stream>>>(emb16, emb, dis, offsets, ends, srcs, out, N);
    } else {
        gather_kernel<false><<<gblocks, B, 0, stream>>>(nullptr, emb, dis, offsets, ends, srcs, out, N);
    }
}

// Round 2
// 215.894 us; speedup vs baseline: 1.1853x; 1.1853x over previous
//
#include <hip/hip_runtime.h>
#include <hip/hip_fp16.h>
#include <math.h>

#define EMB_DIM 128
#define FINE_BITS 8
#define FINE_W 256
#define MAXB 512            // max coarse buckets (N <= 131072)
#define CHUNK 4096          // edges per scatter block

// ---------------------------------------------------------------------------
// K1 (fused): blocks [0,nchunks): col-side coarse scatter; [nchunks,2*nchunks):
// row-side coarse scatter; [2*nchunks, ...): f32->fp16 embedding convert.
// Cursors are RELATIVE (zeroed by memset); absolute base = bucket*slack.
__global__ __launch_bounds__(256) void scatter_cvt_kernel(
    const int* __restrict__ row, const int* __restrict__ col,
    int* __restrict__ colCur, int* __restrict__ rowCur,
    unsigned int* __restrict__ colBucket, unsigned char* __restrict__ rowBucket,
    const float* __restrict__ emb, __half* __restrict__ emb16, long long n8,
    int slack, int nchunks, int e) {
    int bid = blockIdx.x;
    if (bid >= 2 * nchunks) {
        // ---- cvt tail: 8 floats -> 8 halves per thread ----
        long long t = (long long)(bid - 2 * nchunks) * 256 + threadIdx.x;
        if (t < n8) {
            const float4* src = (const float4*)(emb) + t * 2;
            float4 a = src[0];
            float4 b = src[1];
            __half h[8];
            h[0] = __float2half(a.x); h[1] = __float2half(a.y);
            h[2] = __float2half(a.z); h[3] = __float2half(a.w);
            h[4] = __float2half(b.x); h[5] = __float2half(b.y);
            h[6] = __float2half(b.z); h[7] = __float2half(b.w);
            ((uint4*)emb16)[t] = *(const uint4*)h;
        }
        return;
    }
    __shared__ int lh[MAXB], lb[MAXB];
    bool doRow = bid >= nchunks;
    int chunk = doRow ? bid - nchunks : bid;
    int base = chunk * CHUNK;
    int lim = min(base + CHUNK, e);

    for (int t = threadIdx.x; t < MAXB; t += 256) lh[t] = 0;
    __syncthreads();
    if (!doRow) {
        for (int i = base + threadIdx.x; i < lim; i += 256)
            atomicAdd(&lh[col[i] >> FINE_BITS], 1);
        __syncthreads();
        for (int t = threadIdx.x; t < MAXB; t += 256)
            lb[t] = lh[t] ? (t * slack + atomicAdd(&colCur[t], lh[t])) : 0;
        __syncthreads();
        for (int t = threadIdx.x; t < MAXB; t += 256) lh[t] = 0;
        __syncthreads();
        for (int i = base + threadIdx.x; i < lim; i += 256) {
            int c = col[i], r = row[i];
            int cb = c >> FINE_BITS;
            int p = lb[cb] + atomicAdd(&lh[cb], 1);
            if (p < (cb + 1) * slack)
                colBucket[p] = ((unsigned)r << FINE_BITS) | (unsigned)(c & (FINE_W - 1));
        }
    } else {
        for (int i = base + threadIdx.x; i < lim; i += 256)
            atomicAdd(&lh[row[i] >> FINE_BITS], 1);
        __syncthreads();
        for (int t = threadIdx.x; t < MAXB; t += 256)
            lb[t] = lh[t] ? (t * slack + atomicAdd(&rowCur[t], lh[t])) : 0;
        __syncthreads();
        for (int t = threadIdx.x; t < MAXB; t += 256) lh[t] = 0;
        __syncthreads();
        for (int i = base + threadIdx.x; i < lim; i += 256) {
            int r = row[i];
            int rb = r >> FINE_BITS;
            int q = lb[rb] + atomicAdd(&lh[rb], 1);
            if (q < (rb + 1) * slack)
                rowBucket[q] = (unsigned char)(r & (FINE_W - 1));
        }
    }
}

// ---------------------------------------------------------------------------
// K2: 512-thread blocks (FINE_W=256 -> ~4.1K entries/bucket: per-block latency
// halved vs FINE_BITS=9, 782 blocks -> ~3/CU for latency hiding).
// Blocks [0,nbuck): fine counting-sort of one col bucket (LDS hist + inclusive
// scan, absolute placement, zero global atomics). Blocks [nbuck, 2*nbuck):
// row-side fine histogram -> dis = rsqrt(1+deg).
__global__ __launch_bounds__(512) void fine_kernel(
    const unsigned int* __restrict__ colBucket, const int* __restrict__ colCurF,
    const unsigned char* __restrict__ rowBucket, const int* __restrict__ rowCurF,
    int* __restrict__ offsets, int* __restrict__ ends, int* __restrict__ srcs,
    float* __restrict__ dis, int slack, int nbuck, int n) {
    __shared__ int fh[FINE_W];
    __shared__ int sc[FINE_W];
    __shared__ int fb[FINE_W];
    int b0 = blockIdx.x;
    unsigned t = threadIdx.x;
    if (b0 < nbuck) {
        int b = b0;
        int start = b * slack;
        int end = start + min(colCurF[b], slack);
        if (t < FINE_W) fh[t] = 0;
        __syncthreads();
        for (int i = start + (int)t; i < end; i += 512)
            atomicAdd(&fh[colBucket[i] & (FINE_W - 1)], 1);
        __syncthreads();
        if (t < FINE_W) sc[t] = fh[t];
        __syncthreads();
        // inclusive Hillis-Steele scan over 256 bins
        for (int d = 1; d < FINE_W; d <<= 1) {
            int v = (t < FINE_W && t >= (unsigned)d) ? sc[t - d] : 0;
            __syncthreads();
            if (t < FINE_W) sc[t] += v;
            __syncthreads();
        }
        int nodeBase = b << FINE_BITS;
        if (t < FINE_W) {
            int st = start + sc[t] - fh[t];   // exclusive prefix
            fb[t] = st;
            int node = nodeBase + (int)t;
            if (node < n) { offsets[node] = st; ends[node] = st + fh[t]; }
        }
        __syncthreads();
        for (int i = start + (int)t; i < end; i += 512) {
            unsigned v = colBucket[i];
            int p = atomicAdd(&fb[v & (FINE_W - 1)], 1);
            srcs[p] = (int)(v >> FINE_BITS);
        }
    } else {
        int b = b0 - nbuck;
        int start = b * slack;
        int end = start + min(rowCurF[b], slack);
        if (t < FINE_W) fh[t] = 0;
        __syncthreads();
        for (int i = start + (int)t; i < end; i += 512)
            atomicAdd(&fh[rowBucket[i]], 1);
        __syncthreads();
        int nodeBase = b << FINE_BITS;
        if (t < FINE_W) {
            int node = nodeBase + (int)t;
            if (node < n) dis[node] = rsqrtf(1.0f + (float)fh[t]);
        }
    }
}

// ---------------------------------------------------------------------------
// K3: gather (round-0 proven shape: 70us, VGPR=32). 8 lanes/node, 16 floats
// acc/lane, uint4 fp16 loads, unroll-2. Self-loop folded as norm=dc^2.
template <bool FP16>
__global__ __launch_bounds__(256) void gather_kernel(
    const __half* __restrict__ emb16, const float* __restrict__ emb,
    const float* __restrict__ dis, const int* __restrict__ offsets,
    const int* __restrict__ ends, const int* __restrict__ srcs,
    float* __restrict__ out, int n) {
    long long t = (long long)blockIdx.x * blockDim.x + threadIdx.x;
    int node = (int)(t >> 3);
    int lane = (int)(t & 7);
    if (node >= n) return;

    float dc = dis[node];
    float s = dc * dc;
    float4 acc0 = {0, 0, 0, 0}, acc1 = {0, 0, 0, 0};
    float4 acc2 = {0, 0, 0, 0}, acc3 = {0, 0, 0, 0};

#define ACCUM_FP16(SRC, NRM)                                                    \
    {                                                                           \
        const uint4* hrow = (const uint4*)(emb16 + (long long)(SRC) * EMB_DIM); \
        uint4 ha = hrow[lane];                                                  \
        uint4 hb = hrow[lane + 8];                                              \
        const __half2* pa = (const __half2*)&ha;                                \
        const __half2* pb = (const __half2*)&hb;                                \
        float2 f0 = __half22float2(pa[0]), f1 = __half22float2(pa[1]);          \
        float2 f2 = __half22float2(pa[2]), f3 = __half22float2(pa[3]);          \
        float2 g0 = __half22float2(pb[0]), g1 = __half22float2(pb[1]);          \
        float2 g2 = __half22float2(pb[2]), g3 = __half22float2(pb[3]);          \
        acc0.x += (NRM) * f0.x; acc0.y += (NRM) * f0.y;                         \
        acc0.z += (NRM) * f1.x; acc0.w += (NRM) * f1.y;                         \
        acc1.x += (NRM) * f2.x; acc1.y += (NRM) * f2.y;                         \
        acc1.z += (NRM) * f3.x; acc1.w += (NRM) * f3.y;                         \
        acc2.x += (NRM) * g0.x; acc2.y += (NRM) * g0.y;                         \
        acc2.z += (NRM) * g1.x; acc2.w += (NRM) * g1.y;                         \
        acc3.x += (NRM) * g2.x; acc3.y += (NRM) * g2.y;                         \
        acc3.z += (NRM) * g3.x; acc3.w += (NRM) * g3.y;                         \
    }

#define ACCUM_FP32(SRC, NRM)                                                    \
    {                                                                           \
        const float4* frow = (const float4*)(emb + (long long)(SRC) * EMB_DIM); \
        float4 v0 = frow[2 * lane];                                             \
        float4 v1 = frow[2 * lane + 1];                                         \
        float4 v2 = frow[16 + 2 * lane];                                        \
        float4 v3 = frow[16 + 2 * lane + 1];                                    \
        acc0.x += (NRM) * v0.x; acc0.y += (NRM) * v0.y;                         \
        acc0.z += (NRM) * v0.z; acc0.w += (NRM) * v0.w;                         \
        acc1.x += (NRM) * v1.x; acc1.y += (NRM) * v1.y;                         \
        acc1.z += (NRM) * v1.z; acc1.w += (NRM) * v1.w;                         \
        acc2.x += (NRM) * v2.x; acc2.y += (NRM) * v2.y;                         \
        acc2.z += (NRM) * v2.z; acc2.w += (NRM) * v2.w;                         \
        acc3.x += (NRM) * v3.x; acc3.y += (NRM) * v3.y;                         \
        acc3.z += (NRM) * v3.z; acc3.w += (NRM) * v3.w;                         \
    }

    if (FP16) { ACCUM_FP16(node, s); } else { ACCUM_FP32(node, s); }

    int i = offsets[node];
    int end = ends[node];
    for (; i + 2 <= end; i += 2) {
        int s0 = srcs[i], s1 = srcs[i + 1];
        float n0 = dc * dis[s0];
        float n1 = dc * dis[s1];
        if (FP16) { ACCUM_FP16(s0, n0); ACCUM_FP16(s1, n1); }
        else      { ACCUM_FP32(s0, n0); ACCUM_FP32(s1, n1); }
    }
    if (i < end) {
        int s0 = srcs[i];
        float n0 = dc * dis[s0];
        if (FP16) { ACCUM_FP16(s0, n0); } else { ACCUM_FP32(s0, n0); }
    }
#undef ACCUM_FP16
#undef ACCUM_FP32

    float4* orow = (float4*)(out + (long long)node * EMB_DIM);
    orow[2 * lane] = acc0;
    orow[2 * lane + 1] = acc1;
    orow[16 + 2 * lane] = acc2;
    orow[16 + 2 * lane + 1] = acc3;
}

extern "C" void kernel_launch(void* const* d_in, const int* in_sizes, int n_in,
                              void* d_out, int out_size, void* d_ws, size_t ws_size,
                              hipStream_t stream) {
    const int E = in_sizes[0] / 2;            // edge_index is (2, E) int32
    const int N = in_sizes[1] / EMB_DIM;      // embedding is (N, 128) f32
    const int nbuck = (N + FINE_W - 1) >> FINE_BITS;   // 391 for N=100000

    const int* edge_index = (const int*)d_in[0];
    const int* row = edge_index;              // sources
    const int* col = edge_index + E;          // destinations
    const float* emb = (const float*)d_in[1];
    float* out = (float*)d_out;

    // slack per bucket: mean + 25% + 1024 (>>10 sigma for random edges)
    const int expected = (int)(((long long)E * FINE_W + N - 1) / N);
    const int slack = expected + (expected >> 2) + 1024;
    const size_t bucketEntries = (size_t)nbuck * slack;

    char* ws = (char*)d_ws;
    size_t off = 0;
    auto alloc = [&](size_t bytes) -> void* {
        off = (off + 255) & ~(size_t)255;
        void* p = ws + off;
        off += bytes;
        return p;
    };

    size_t szEmb16 = (size_t)N * EMB_DIM * 2;
    size_t needCommon = (size_t)MAXB * 8 + (size_t)N * 12 +
                        bucketEntries * 9 + 16 * 256;
    bool useFp16 = (needCommon + szEmb16) <= ws_size;

    int*            colCur    = (int*)alloc((size_t)MAXB * 4);
    int*            rowCur    = (int*)alloc((size_t)MAXB * 4);   // adjacent to colCur
    int*            offsets   = (int*)alloc((size_t)N * 4);
    int*            ends      = (int*)alloc((size_t)N * 4);
    float*          dis       = (float*)alloc((size_t)N * 4);
    unsigned int*   colBucket = (unsigned int*)alloc(bucketEntries * 4);
    unsigned char*  rowBucket = (unsigned char*)alloc(bucketEntries);
    int*            srcs      = (int*)alloc(bucketEntries * 4);
    __half*         emb16     = useFp16 ? (__half*)alloc(szEmb16) : (__half*)nullptr;

    const int B = 256;
    const int nchunks = (E + CHUNK - 1) / CHUNK;
    long long n8 = useFp16 ? (long long)N * EMB_DIM / 8 : 0;
    int cvtBlocks = useFp16 ? (int)((n8 + B - 1) / B) : 0;

    // zero both relative cursor arrays (adjacent, each MAXB*4)
    hipMemsetAsync(colCur, 0, (size_t)MAXB * 8, stream);

    scatter_cvt_kernel<<<2 * nchunks + cvtBlocks, B, 0, stream>>>(
        row, col, colCur, rowCur, colBucket, rowBucket,
        emb, emb16, n8, slack, nchunks, E);

    fine_kernel<<<2 * nbuck, 512, 0, stream>>>(
        colBucket, colCur, rowBucket, rowCur, offsets, ends, srcs, dis, slack, nbuck, N);

    long long gather_threads = (long long)N * 8;
    int gblocks = (int)((gather_threads + B - 1) / B);
    if (useFp16) {
        gather_kernel<true><<<gblocks, B, 0, stream>>>(emb16, emb, dis, offsets, ends, srcs, out, N);
    } else {
        gather_kernel<false><<<gblocks, B, 0, stream>>>(nullptr, emb, dis, offsets, ends, srcs, out, N);
    }
}